// Round 7
// baseline (4500.777 us; speedup 1.0000x reference)
//
#include <hip/hip_runtime.h>

#define BATCH 16
#define NPTS 16384
#define MCENT 1024
#define NSAMPLE 32
#define FTHR 1024
#define FWAVE 16
#define FPPT 16

// ---- Morton code: 10 bits, (x:4, y:3, z:3)
__device__ __forceinline__ unsigned morton10(float x, float y, float z) {
    int qx = (int)(x * 16.0f); qx = qx < 0 ? 0 : (qx > 15 ? 15 : qx);
    int qy = (int)(y * 8.0f);  qy = qy < 0 ? 0 : (qy > 7 ? 7 : qy);
    int qz = (int)(z * 8.0f);  qz = qz < 0 ? 0 : (qz > 7 ? 7 : qz);
    unsigned c = 0;
    c |= (unsigned)(qx & 1) | ((unsigned)(qy & 1) << 1) | ((unsigned)(qz & 1) << 2);
    c |= (((unsigned)(qx >> 1) & 1) << 3) | (((unsigned)(qy >> 1) & 1) << 4) | (((unsigned)(qz >> 1) & 1) << 5);
    c |= (((unsigned)(qx >> 2) & 1) << 6) | (((unsigned)(qy >> 2) & 1) << 7) | (((unsigned)(qz >> 2) & 1) << 8);
    c |= (((unsigned)(qx >> 3) & 1) << 9);
    return c;
}

__device__ __forceinline__ unsigned long long shflxor_u64(unsigned long long v, int m) {
    int lo = __shfl_xor((int)(unsigned)v, m, 64);
    int hi = __shfl_xor((int)(unsigned)(v >> 32), m, 64);
    return ((unsigned long long)(unsigned)hi << 32) | (unsigned)lo;
}

// ---------------- setup: Morton counting-sort per batch ----------------
__global__ __launch_bounds__(1024) void sort_kernel(const float* __restrict__ xyz,
                                                    float4* __restrict__ sorted) {
    const int b = blockIdx.x;
    const int tid = threadIdx.x;
    const int lane = tid & 63;
    const int wid = tid >> 6;
    const float* xb = xyz + (size_t)b * NPTS * 3;
    float4* sb = sorted + (size_t)b * NPTS;

    __shared__ unsigned hist[1024];
    __shared__ unsigned wsum[16];
    hist[tid] = 0;
    __syncthreads();

    float mx[16], my[16], mz[16];
    unsigned mc[16];
#pragma unroll
    for (int j = 0; j < 16; ++j) {
        int p = j * 1024 + tid;
        mx[j] = xb[p * 3 + 0];
        my[j] = xb[p * 3 + 1];
        mz[j] = xb[p * 3 + 2];
        mc[j] = morton10(mx[j], my[j], mz[j]);
        atomicAdd(&hist[mc[j]], 1u);
    }
    __syncthreads();

    unsigned orig = hist[tid];
    unsigned v = orig;
#pragma unroll
    for (int off = 1; off < 64; off <<= 1) {
        unsigned n = __shfl_up(v, off);
        if (lane >= off) v += n;
    }
    if (lane == 63) wsum[wid] = v;
    __syncthreads();
    if (wid == 0 && lane < 16) {
        unsigned s = wsum[lane];
#pragma unroll
        for (int off = 1; off < 16; off <<= 1) {
            unsigned n = __shfl_up(s, off);
            if (lane >= off) s += n;
        }
        wsum[lane] = s;
    }
    __syncthreads();
    unsigned base = v - orig + (wid > 0 ? wsum[wid - 1] : 0u);
    __syncthreads();
    hist[tid] = base;
    __syncthreads();

#pragma unroll
    for (int j = 0; j < 16; ++j) {
        int p = j * 1024 + tid;
        unsigned pos = atomicAdd(&hist[mc[j]], 1u);
        sb[pos] = make_float4(mx[j], my[j], mz[j], __int_as_float(p));
    }
}

// ---------------- FPS: no arrays — named-scalar md, xyz reloaded from L2 ----------------
#define UPD(V, MD)                                                              \
    {                                                                           \
        float dx = V.x - cx;                                                    \
        float dy = V.y - cy;                                                    \
        float dz = V.z - cz;                                                    \
        float d = dx * dx + dy * dy;                                            \
        d = d + dz * dz;                                                        \
        float nm = fminf(MD, d);                                                \
        MD = nm;                                                                \
        int pj = __float_as_int(V.w);                                           \
        if (nm > bv || (nm == bv && pj < bpid)) {                               \
            bv = nm; bpid = pj; bx = V.x; by = V.y; bz = V.z;                   \
        }                                                                       \
    }

__global__ __attribute__((amdgpu_waves_per_eu(4, 4)))
__launch_bounds__(FTHR) void fps_kernel(const float* __restrict__ xyz,
                                        const float4* __restrict__ sorted,
                                        float* __restrict__ cent_out) {
#pragma clang fp contract(off)
    const int b = blockIdx.x;
    const int tid = threadIdx.x;
    const int wid = tid >> 6;
    const float4* sp = sorted + (size_t)b * NPTS + tid * FPPT;
    const float* xb = xyz + (size_t)b * NPTS * 3;
    float* cb = cent_out + (size_t)b * MCENT * 3;

    // bbox of this thread's 16 spatially-local (Morton-sorted) points
    float lx = 1e30f, ly = 1e30f, lz = 1e30f, hx = -1e30f, hy = -1e30f, hz = -1e30f;
#pragma unroll
    for (int j = 0; j < FPPT; ++j) {
        float4 v = sp[j];
        lx = fminf(lx, v.x); hx = fmaxf(hx, v.x);
        ly = fminf(ly, v.y); hy = fmaxf(hy, v.y);
        lz = fminf(lz, v.z); hz = fmaxf(hz, v.z);
    }

    // min-dist state: 16 NAMED scalars (no alloca -> cannot be demoted)
    float md0 = 1e10f, md1 = 1e10f, md2 = 1e10f, md3 = 1e10f;
    float md4 = 1e10f, md5 = 1e10f, md6 = 1e10f, md7 = 1e10f;
    float md8 = 1e10f, md9 = 1e10f, md10 = 1e10f, md11 = 1e10f;
    float md12 = 1e10f, md13 = 1e10f, md14 = 1e10f, md15 = 1e10f;

    __shared__ unsigned long long skey[2][FWAVE];
    __shared__ float4 scd[2][FWAVE];
    __shared__ float cent_lds[MCENT * 3];

    float cx = xb[0], cy = xb[1], cz = xb[2];

    float bv = -1.0f; int bpid = 0x7fffffff;
    float bx = 0.f, by = 0.f, bz = 0.f;
    unsigned long long mykey = 0, wkey = 0;

    for (int m = 0; m < MCENT; ++m) {
        if (tid == 0) {
            cent_lds[m * 3 + 0] = cx;
            cent_lds[m * 3 + 1] = cy;
            cent_lds[m * 3 + 2] = cz;
        }
        if (m == MCENT - 1) break;

        // exact prune: provably no md in this thread can change -> skip
        float tx = fmaxf(fmaxf(lx - cx, cx - hx), 0.0f);
        float ty = fmaxf(fmaxf(ly - cy, cy - hy), 0.0f);
        float tz = fmaxf(fmaxf(lz - cz, cz - hz), 0.0f);
        float lb = tx * tx + ty * ty;
        lb = lb + tz * tz;
        bool active = (m == 0) || (lb * 0.999f < bv);

        if (active) {
            bv = -1.0f; bpid = 0x7fffffff;
            // batch 1: 8 independent L2 loads, then compute
            {
                float4 a0 = sp[0], a1 = sp[1], a2 = sp[2], a3 = sp[3];
                float4 a4 = sp[4], a5 = sp[5], a6 = sp[6], a7 = sp[7];
                UPD(a0, md0) UPD(a1, md1) UPD(a2, md2) UPD(a3, md3)
                UPD(a4, md4) UPD(a5, md5) UPD(a6, md6) UPD(a7, md7)
            }
            // batch 2
            {
                float4 a0 = sp[8], a1 = sp[9], a2 = sp[10], a3 = sp[11];
                float4 a4 = sp[12], a5 = sp[13], a6 = sp[14], a7 = sp[15];
                UPD(a0, md8) UPD(a1, md9) UPD(a2, md10) UPD(a3, md11)
                UPD(a4, md12) UPD(a5, md13) UPD(a6, md14) UPD(a7, md15)
            }
            mykey = ((unsigned long long)__float_as_uint(bv) << 32)
                  | (unsigned)(((16383 - bpid) << 4) | wid);
        }

        if (__any(active)) {
            unsigned long long k = mykey;
#pragma unroll
            for (int off = 1; off <= 32; off <<= 1) {
                unsigned long long o = shflxor_u64(k, off);
                if (o > k) k = o;
            }
            wkey = k;
        }
        const int pb = m & 1;
        if (mykey == wkey) {  // unique owner (pid embedded); runs every iter
            skey[pb][wid] = wkey;
            scd[pb][wid] = make_float4(bx, by, bz, 0.0f);
        }
        __syncthreads();

        // redundant per-wave reduce of the 16 slots (8 pairs + depth-4 tree)
        unsigned long long t0, t1, t2, t3, t4, t5, t6, t7;
        {
            unsigned long long a, c;
            a = skey[pb][0];  c = skey[pb][1];  t0 = a > c ? a : c;
            a = skey[pb][2];  c = skey[pb][3];  t1 = a > c ? a : c;
            a = skey[pb][4];  c = skey[pb][5];  t2 = a > c ? a : c;
            a = skey[pb][6];  c = skey[pb][7];  t3 = a > c ? a : c;
            a = skey[pb][8];  c = skey[pb][9];  t4 = a > c ? a : c;
            a = skey[pb][10]; c = skey[pb][11]; t5 = a > c ? a : c;
            a = skey[pb][12]; c = skey[pb][13]; t6 = a > c ? a : c;
            a = skey[pb][14]; c = skey[pb][15]; t7 = a > c ? a : c;
        }
        if (t4 > t0) t0 = t4;
        if (t5 > t1) t1 = t5;
        if (t6 > t2) t2 = t6;
        if (t7 > t3) t3 = t7;
        if (t2 > t0) t0 = t2;
        if (t3 > t1) t1 = t3;
        if (t1 > t0) t0 = t1;
        float4 w = scd[pb][(unsigned)t0 & 15u];
        cx = w.x; cy = w.y; cz = w.z;
    }

    __syncthreads();
    for (int i = tid; i < MCENT * 3; i += FTHR) cb[i] = cent_lds[i];
}

// ---------------- Ball query + group ----------------
__global__ __launch_bounds__(256) void ballq_kernel(const float* __restrict__ xyz,
                                                    const float* __restrict__ cent,
                                                    float* __restrict__ grouped) {
#pragma clang fp contract(off)
    const int lane = threadIdx.x & 63;
    const int wib = threadIdx.x >> 6;
    const int cid = blockIdx.x * 4 + wib;
    const int b = cid >> 10;
    const float* xb = xyz + (size_t)b * NPTS * 3;
    const float* c = cent + (size_t)cid * 3;
    float cx = c[0], cy = c[1], cz = c[2];
    float* g = grouped + (size_t)cid * NSAMPLE * 3;

    const float R2 = (float)(0.1 * 0.1);

    int total = 0;
    int first_p = -1;

    for (int p0 = 0; p0 < NPTS && total < NSAMPLE; p0 += 64) {
        int p = p0 + lane;
        float x = xb[p * 3 + 0];
        float y = xb[p * 3 + 1];
        float z = xb[p * 3 + 2];
        float dx = x - cx;
        float dy = y - cy;
        float dz = z - cz;
        float d = dx * dx + dy * dy;
        d = d + dz * dz;
        bool hit = d < R2;
        unsigned long long mask = __ballot(hit);
        if (hit) {
            unsigned int mb = __builtin_amdgcn_mbcnt_lo((unsigned int)mask, 0u);
            mb = __builtin_amdgcn_mbcnt_hi((unsigned int)(mask >> 32), mb);
            int pos = total + (int)mb;
            if (pos < NSAMPLE) {
                g[pos * 3 + 0] = dx;
                g[pos * 3 + 1] = dy;
                g[pos * 3 + 2] = dz;
            }
        }
        if (first_p < 0 && mask != 0ull) first_p = p0 + __builtin_ctzll(mask);
        total += __popcll(mask);
    }

    int sel = total < NSAMPLE ? total : NSAMPLE;
    if (sel < NSAMPLE) {
        float fx = xb[first_p * 3 + 0] - cx;
        float fy = xb[first_p * 3 + 1] - cy;
        float fz = xb[first_p * 3 + 2] - cz;
        int s = lane;
        if (s >= sel && s < NSAMPLE) {
            g[s * 3 + 0] = fx;
            g[s * 3 + 1] = fy;
            g[s * 3 + 2] = fz;
        }
    }
}

extern "C" void kernel_launch(void* const* d_in, const int* in_sizes, int n_in,
                              void* d_out, int out_size, void* d_ws, size_t ws_size,
                              hipStream_t stream) {
    const float* xyz = (const float*)d_in[0];
    float* out = (float*)d_out;
    float* grouped = out;
    float* cent = out + (size_t)BATCH * MCENT * NSAMPLE * 3;
    float4* sorted = (float4*)d_ws;  // 4 MiB

    sort_kernel<<<BATCH, 1024, 0, stream>>>(xyz, sorted);
    fps_kernel<<<BATCH, FTHR, 0, stream>>>(xyz, sorted, cent);
    ballq_kernel<<<(BATCH * MCENT) / 4, 256, 0, stream>>>(xyz, cent, grouped);
}

// Round 8
// 4020.292 us; speedup vs baseline: 1.1195x; 1.1195x over previous
//
#include <hip/hip_runtime.h>

#define BATCH 16
#define NPTS 16384
#define MCENT 1024
#define NSAMPLE 32
#define FTHR 1024
#define FWAVE 16

// ---- Morton code: 10 bits, (x:4, y:3, z:3)
__device__ __forceinline__ unsigned morton10(float x, float y, float z) {
    int qx = (int)(x * 16.0f); qx = qx < 0 ? 0 : (qx > 15 ? 15 : qx);
    int qy = (int)(y * 8.0f);  qy = qy < 0 ? 0 : (qy > 7 ? 7 : qy);
    int qz = (int)(z * 8.0f);  qz = qz < 0 ? 0 : (qz > 7 ? 7 : qz);
    unsigned c = 0;
    c |= (unsigned)(qx & 1) | ((unsigned)(qy & 1) << 1) | ((unsigned)(qz & 1) << 2);
    c |= (((unsigned)(qx >> 1) & 1) << 3) | (((unsigned)(qy >> 1) & 1) << 4) | (((unsigned)(qz >> 1) & 1) << 5);
    c |= (((unsigned)(qx >> 2) & 1) << 6) | (((unsigned)(qy >> 2) & 1) << 7) | (((unsigned)(qz >> 2) & 1) << 8);
    c |= (((unsigned)(qx >> 3) & 1) << 9);
    return c;
}

__device__ __forceinline__ unsigned long long shflxor_u64(unsigned long long v, int m) {
    int lo = __shfl_xor((int)(unsigned)v, m, 64);
    int hi = __shfl_xor((int)(unsigned)(v >> 32), m, 64);
    return ((unsigned long long)(unsigned)hi << 32) | (unsigned)lo;
}

// ---------------- setup: Morton counting-sort per batch ----------------
__global__ __launch_bounds__(1024) void sort_kernel(const float* __restrict__ xyz,
                                                    float4* __restrict__ sorted) {
    const int b = blockIdx.x;
    const int tid = threadIdx.x;
    const int lane = tid & 63;
    const int wid = tid >> 6;
    const float* xb = xyz + (size_t)b * NPTS * 3;
    float4* sb = sorted + (size_t)b * NPTS;

    __shared__ unsigned hist[1024];
    __shared__ unsigned wsum[16];
    hist[tid] = 0;
    __syncthreads();

    float mx[16], my[16], mz[16];
    unsigned mc[16];
#pragma unroll
    for (int j = 0; j < 16; ++j) {
        int p = j * 1024 + tid;
        mx[j] = xb[p * 3 + 0];
        my[j] = xb[p * 3 + 1];
        mz[j] = xb[p * 3 + 2];
        mc[j] = morton10(mx[j], my[j], mz[j]);
        atomicAdd(&hist[mc[j]], 1u);
    }
    __syncthreads();

    unsigned orig = hist[tid];
    unsigned v = orig;
#pragma unroll
    for (int off = 1; off < 64; off <<= 1) {
        unsigned n = __shfl_up(v, off);
        if (lane >= off) v += n;
    }
    if (lane == 63) wsum[wid] = v;
    __syncthreads();
    if (wid == 0 && lane < 16) {
        unsigned s = wsum[lane];
#pragma unroll
        for (int off = 1; off < 16; off <<= 1) {
            unsigned n = __shfl_up(s, off);
            if (lane >= off) s += n;
        }
        wsum[lane] = s;
    }
    __syncthreads();
    unsigned base = v - orig + (wid > 0 ? wsum[wid - 1] : 0u);
    __syncthreads();
    hist[tid] = base;
    __syncthreads();

#pragma unroll
    for (int j = 0; j < 16; ++j) {
        int p = j * 1024 + tid;
        unsigned pos = atomicAdd(&hist[mc[j]], 1u);
        sb[pos] = make_float4(mx[j], my[j], mz[j], __int_as_float(p));
    }
}

// ---------------- FPS: fully register-resident, named scalars only ----------------
#define LOADP(j, pp, odd)                                                       \
    {                                                                           \
        float4 v = sp[j];                                                       \
        px##j = v.x; py##j = v.y; pz##j = v.z; md##j = 1e10f;                   \
        if (odd) pp |= ((unsigned)__float_as_int(v.w)) << 16;                   \
        else     pp  = (unsigned)__float_as_int(v.w);                           \
        lx = fminf(lx, v.x); hx = fmaxf(hx, v.x);                               \
        ly = fminf(ly, v.y); hy = fmaxf(hy, v.y);                               \
        lz = fminf(lz, v.z); hz = fmaxf(hz, v.z);                               \
    }

#define UPD(j, pidexpr)                                                         \
    {                                                                           \
        float dx = px##j - cx;                                                  \
        float dy = py##j - cy;                                                  \
        float dz = pz##j - cz;                                                  \
        float d = dx * dx + dy * dy;                                            \
        d = d + dz * dz;                                                        \
        float nm = fminf(md##j, d);                                             \
        md##j = nm;                                                             \
        int pj = (int)(pidexpr);                                                \
        if (nm > bv || (nm == bv && pj < bpid)) {                               \
            bv = nm; bpid = pj; bx = px##j; by = py##j; bz = pz##j;             \
        }                                                                       \
    }

__global__ __attribute__((amdgpu_waves_per_eu(4, 4)))
__launch_bounds__(FTHR) void fps_kernel(const float* __restrict__ xyz,
                                        const float4* __restrict__ sorted,
                                        float* __restrict__ cent_out) {
#pragma clang fp contract(off)
    const int b = blockIdx.x;
    const int tid = threadIdx.x;
    const int wid = tid >> 6;
    const float4* sp = sorted + (size_t)b * NPTS + tid * 16;
    const float* xb = xyz + (size_t)b * NPTS * 3;
    float* cb = cent_out + (size_t)b * MCENT * 3;

    float px0, px1, px2, px3, px4, px5, px6, px7, px8, px9, px10, px11, px12, px13, px14, px15;
    float py0, py1, py2, py3, py4, py5, py6, py7, py8, py9, py10, py11, py12, py13, py14, py15;
    float pz0, pz1, pz2, pz3, pz4, pz5, pz6, pz7, pz8, pz9, pz10, pz11, pz12, pz13, pz14, pz15;
    float md0, md1, md2, md3, md4, md5, md6, md7, md8, md9, md10, md11, md12, md13, md14, md15;
    unsigned pp0, pp1, pp2, pp3, pp4, pp5, pp6, pp7;
    float lx = 1e30f, ly = 1e30f, lz = 1e30f, hx = -1e30f, hy = -1e30f, hz = -1e30f;

    LOADP(0, pp0, 0)  LOADP(1, pp0, 1)  LOADP(2, pp1, 0)  LOADP(3, pp1, 1)
    LOADP(4, pp2, 0)  LOADP(5, pp2, 1)  LOADP(6, pp3, 0)  LOADP(7, pp3, 1)
    LOADP(8, pp4, 0)  LOADP(9, pp4, 1)  LOADP(10, pp5, 0) LOADP(11, pp5, 1)
    LOADP(12, pp6, 0) LOADP(13, pp6, 1) LOADP(14, pp7, 0) LOADP(15, pp7, 1)

    __shared__ unsigned long long skey[2][FWAVE];
    __shared__ float4 scd[2][FWAVE];
    __shared__ float cent_lds[MCENT * 3];

    float cx = xb[0], cy = xb[1], cz = xb[2];

    float bv = -1.0f; int bpid = 0x7fffffff;
    float bx = 0.f, by = 0.f, bz = 0.f;
    unsigned long long mykey = 0, wkey = 0;

    for (int m = 0; m < MCENT; ++m) {
        if (tid == 0) {
            cent_lds[m * 3 + 0] = cx;
            cent_lds[m * 3 + 1] = cy;
            cent_lds[m * 3 + 2] = cz;
        }
        if (m == MCENT - 1) break;

        // exact prune: provably no md in this thread can change -> skip update
        float tx = fmaxf(fmaxf(lx - cx, cx - hx), 0.0f);
        float ty = fmaxf(fmaxf(ly - cy, cy - hy), 0.0f);
        float tz = fmaxf(fmaxf(lz - cz, cz - hz), 0.0f);
        float lb = tx * tx + ty * ty;
        lb = lb + tz * tz;
        bool active = (m == 0) || (lb * 0.999f < bv);

        if (active) {
            bv = -1.0f; bpid = 0x7fffffff;
            UPD(0,  pp0 & 0xffffu) UPD(1,  pp0 >> 16)
            UPD(2,  pp1 & 0xffffu) UPD(3,  pp1 >> 16)
            UPD(4,  pp2 & 0xffffu) UPD(5,  pp2 >> 16)
            UPD(6,  pp3 & 0xffffu) UPD(7,  pp3 >> 16)
            UPD(8,  pp4 & 0xffffu) UPD(9,  pp4 >> 16)
            UPD(10, pp5 & 0xffffu) UPD(11, pp5 >> 16)
            UPD(12, pp6 & 0xffffu) UPD(13, pp6 >> 16)
            UPD(14, pp7 & 0xffffu) UPD(15, pp7 >> 16)
            mykey = ((unsigned long long)__float_as_uint(bv) << 32)
                  | (unsigned)(((16383 - bpid) << 4) | wid);
        }

        if (__any(active)) {
            unsigned long long k = mykey;
#pragma unroll
            for (int off = 1; off <= 32; off <<= 1) {
                unsigned long long o = shflxor_u64(k, off);
                if (o > k) k = o;
            }
            wkey = k;
        }
        const int pb = m & 1;
        if (mykey == wkey) {  // unique owner (pid embedded); runs every iter
            skey[pb][wid] = wkey;
            scd[pb][wid] = make_float4(bx, by, bz, 0.0f);
        }
        __syncthreads();

        // redundant per-wave reduce of 16 slots (8 pairs + depth-3 tree)
        unsigned long long t0, t1, t2, t3, t4, t5, t6, t7;
        {
            unsigned long long a, c;
            a = skey[pb][0];  c = skey[pb][1];  t0 = a > c ? a : c;
            a = skey[pb][2];  c = skey[pb][3];  t1 = a > c ? a : c;
            a = skey[pb][4];  c = skey[pb][5];  t2 = a > c ? a : c;
            a = skey[pb][6];  c = skey[pb][7];  t3 = a > c ? a : c;
            a = skey[pb][8];  c = skey[pb][9];  t4 = a > c ? a : c;
            a = skey[pb][10]; c = skey[pb][11]; t5 = a > c ? a : c;
            a = skey[pb][12]; c = skey[pb][13]; t6 = a > c ? a : c;
            a = skey[pb][14]; c = skey[pb][15]; t7 = a > c ? a : c;
        }
        if (t4 > t0) t0 = t4;
        if (t5 > t1) t1 = t5;
        if (t6 > t2) t2 = t6;
        if (t7 > t3) t3 = t7;
        if (t2 > t0) t0 = t2;
        if (t3 > t1) t1 = t3;
        if (t1 > t0) t0 = t1;
        float4 w = scd[pb][(unsigned)t0 & 15u];
        cx = w.x; cy = w.y; cz = w.z;
    }

    __syncthreads();
    for (int i = tid; i < MCENT * 3; i += FTHR) cb[i] = cent_lds[i];
}

// ---------------- Ball query + group ----------------
__global__ __launch_bounds__(256) void ballq_kernel(const float* __restrict__ xyz,
                                                    const float* __restrict__ cent,
                                                    float* __restrict__ grouped) {
#pragma clang fp contract(off)
    const int lane = threadIdx.x & 63;
    const int wib = threadIdx.x >> 6;
    const int cid = blockIdx.x * 4 + wib;
    const int b = cid >> 10;
    const float* xb = xyz + (size_t)b * NPTS * 3;
    const float* c = cent + (size_t)cid * 3;
    float cx = c[0], cy = c[1], cz = c[2];
    float* g = grouped + (size_t)cid * NSAMPLE * 3;

    const float R2 = (float)(0.1 * 0.1);

    int total = 0;
    int first_p = -1;

    for (int p0 = 0; p0 < NPTS && total < NSAMPLE; p0 += 64) {
        int p = p0 + lane;
        float x = xb[p * 3 + 0];
        float y = xb[p * 3 + 1];
        float z = xb[p * 3 + 2];
        float dx = x - cx;
        float dy = y - cy;
        float dz = z - cz;
        float d = dx * dx + dy * dy;
        d = d + dz * dz;
        bool hit = d < R2;
        unsigned long long mask = __ballot(hit);
        if (hit) {
            unsigned int mb = __builtin_amdgcn_mbcnt_lo((unsigned int)mask, 0u);
            mb = __builtin_amdgcn_mbcnt_hi((unsigned int)(mask >> 32), mb);
            int pos = total + (int)mb;
            if (pos < NSAMPLE) {
                g[pos * 3 + 0] = dx;
                g[pos * 3 + 1] = dy;
                g[pos * 3 + 2] = dz;
            }
        }
        if (first_p < 0 && mask != 0ull) first_p = p0 + __builtin_ctzll(mask);
        total += __popcll(mask);
    }

    int sel = total < NSAMPLE ? total : NSAMPLE;
    if (sel < NSAMPLE) {
        float fx = xb[first_p * 3 + 0] - cx;
        float fy = xb[first_p * 3 + 1] - cy;
        float fz = xb[first_p * 3 + 2] - cz;
        int s = lane;
        if (s >= sel && s < NSAMPLE) {
            g[s * 3 + 0] = fx;
            g[s * 3 + 1] = fy;
            g[s * 3 + 2] = fz;
        }
    }
}

extern "C" void kernel_launch(void* const* d_in, const int* in_sizes, int n_in,
                              void* d_out, int out_size, void* d_ws, size_t ws_size,
                              hipStream_t stream) {
    const float* xyz = (const float*)d_in[0];
    float* out = (float*)d_out;
    float* grouped = out;
    float* cent = out + (size_t)BATCH * MCENT * NSAMPLE * 3;
    float4* sorted = (float4*)d_ws;  // 4 MiB

    sort_kernel<<<BATCH, 1024, 0, stream>>>(xyz, sorted);
    fps_kernel<<<BATCH, FTHR, 0, stream>>>(xyz, sorted, cent);
    ballq_kernel<<<(BATCH * MCENT) / 4, 256, 0, stream>>>(xyz, cent, grouped);
}

// Round 9
// 3452.357 us; speedup vs baseline: 1.3037x; 1.1645x over previous
//
#include <hip/hip_runtime.h>

#define BATCH 16
#define NPTS 16384
#define MCENT 1024
#define NSAMPLE 32
#define FTHR 512
#define FWAVE 8
#define SEG 2048   // points per wave

// ---- Morton code: 10 bits, (x:4, y:3, z:3)
__device__ __forceinline__ unsigned morton10(float x, float y, float z) {
    int qx = (int)(x * 16.0f); qx = qx < 0 ? 0 : (qx > 15 ? 15 : qx);
    int qy = (int)(y * 8.0f);  qy = qy < 0 ? 0 : (qy > 7 ? 7 : qy);
    int qz = (int)(z * 8.0f);  qz = qz < 0 ? 0 : (qz > 7 ? 7 : qz);
    unsigned c = 0;
    c |= (unsigned)(qx & 1) | ((unsigned)(qy & 1) << 1) | ((unsigned)(qz & 1) << 2);
    c |= (((unsigned)(qx >> 1) & 1) << 3) | (((unsigned)(qy >> 1) & 1) << 4) | (((unsigned)(qz >> 1) & 1) << 5);
    c |= (((unsigned)(qx >> 2) & 1) << 6) | (((unsigned)(qy >> 2) & 1) << 7) | (((unsigned)(qz >> 2) & 1) << 8);
    c |= (((unsigned)(qx >> 3) & 1) << 9);
    return c;
}

__device__ __forceinline__ unsigned long long shflxor_u64(unsigned long long v, int m) {
    int lo = __shfl_xor((int)(unsigned)v, m, 64);
    int hi = __shfl_xor((int)(unsigned)(v >> 32), m, 64);
    return ((unsigned long long)(unsigned)hi << 32) | (unsigned)lo;
}

// ---------------- setup: Morton counting-sort per batch ----------------
__global__ __launch_bounds__(1024) void sort_kernel(const float* __restrict__ xyz,
                                                    float4* __restrict__ sorted) {
    const int b = blockIdx.x;
    const int tid = threadIdx.x;
    const int lane = tid & 63;
    const int wid = tid >> 6;
    const float* xb = xyz + (size_t)b * NPTS * 3;
    float4* sb = sorted + (size_t)b * NPTS;

    __shared__ unsigned hist[1024];
    __shared__ unsigned wsum[16];
    hist[tid] = 0;
    __syncthreads();

    float mx[16], my[16], mz[16];
    unsigned mc[16];
#pragma unroll
    for (int j = 0; j < 16; ++j) {
        int p = j * 1024 + tid;
        mx[j] = xb[p * 3 + 0];
        my[j] = xb[p * 3 + 1];
        mz[j] = xb[p * 3 + 2];
        mc[j] = morton10(mx[j], my[j], mz[j]);
        atomicAdd(&hist[mc[j]], 1u);
    }
    __syncthreads();

    unsigned orig = hist[tid];
    unsigned v = orig;
#pragma unroll
    for (int off = 1; off < 64; off <<= 1) {
        unsigned n = __shfl_up(v, off);
        if (lane >= off) v += n;
    }
    if (lane == 63) wsum[wid] = v;
    __syncthreads();
    if (wid == 0 && lane < 16) {
        unsigned s = wsum[lane];
#pragma unroll
        for (int off = 1; off < 16; off <<= 1) {
            unsigned n = __shfl_up(s, off);
            if (lane >= off) s += n;
        }
        wsum[lane] = s;
    }
    __syncthreads();
    unsigned base = v - orig + (wid > 0 ? wsum[wid - 1] : 0u);
    __syncthreads();
    hist[tid] = base;
    __syncthreads();

#pragma unroll
    for (int j = 0; j < 16; ++j) {
        int p = j * 1024 + tid;
        unsigned pos = atomicAdd(&hist[mc[j]], 1u);
        sb[pos] = make_float4(mx[j], my[j], mz[j], __int_as_float(p));
    }
}

// ---------------- FPS: 512 thr, md-only register state, coalesced L2 reload ----
#define UPD(MD, V)                                                              \
    {                                                                           \
        float dx = V.x - cx;                                                    \
        float dy = V.y - cy;                                                    \
        float dz = V.z - cz;                                                    \
        float d = dx * dx + dy * dy;                                            \
        d = d + dz * dz;                                                        \
        float nm = fminf(MD, d);                                                \
        MD = nm;                                                                \
        int pj = __float_as_int(V.w);                                           \
        if (nm > bv || (nm == bv && pj < bpid)) {                               \
            bv = nm; bpid = pj; bx = V.x; by = V.y; bz = V.z;                   \
        }                                                                       \
    }

// batch of 8 coalesced loads (lane stride 16B) then 8 updates
#define BATCH8(K, M0, M1, M2, M3, M4, M5, M6, M7)                               \
    {                                                                           \
        float4 a0 = spl[((K)*8 + 0) * 64];                                      \
        float4 a1 = spl[((K)*8 + 1) * 64];                                      \
        float4 a2 = spl[((K)*8 + 2) * 64];                                      \
        float4 a3 = spl[((K)*8 + 3) * 64];                                      \
        float4 a4 = spl[((K)*8 + 4) * 64];                                      \
        float4 a5 = spl[((K)*8 + 5) * 64];                                      \
        float4 a6 = spl[((K)*8 + 6) * 64];                                      \
        float4 a7 = spl[((K)*8 + 7) * 64];                                      \
        UPD(M0, a0) UPD(M1, a1) UPD(M2, a2) UPD(M3, a3)                         \
        UPD(M4, a4) UPD(M5, a5) UPD(M6, a6) UPD(M7, a7)                         \
    }

__global__ __launch_bounds__(FTHR) void fps_kernel(const float* __restrict__ xyz,
                                                   const float4* __restrict__ sorted,
                                                   float* __restrict__ cent_out) {
#pragma clang fp contract(off)
    const int b = blockIdx.x;
    const int tid = threadIdx.x;
    const int lane = tid & 63;
    const int wid = tid >> 6;
    // wave-contiguous segment; lane l handles points j*64+l (coalesced)
    const float4* spl = sorted + (size_t)b * NPTS + wid * SEG + lane;
    const float* xb = xyz + (size_t)b * NPTS * 3;
    float* cb = cent_out + (size_t)b * MCENT * 3;

    // min-dist state: 32 named scalars (cannot be demoted)
    float md0 = 1e10f, md1 = 1e10f, md2 = 1e10f, md3 = 1e10f;
    float md4 = 1e10f, md5 = 1e10f, md6 = 1e10f, md7 = 1e10f;
    float md8 = 1e10f, md9 = 1e10f, md10 = 1e10f, md11 = 1e10f;
    float md12 = 1e10f, md13 = 1e10f, md14 = 1e10f, md15 = 1e10f;
    float md16 = 1e10f, md17 = 1e10f, md18 = 1e10f, md19 = 1e10f;
    float md20 = 1e10f, md21 = 1e10f, md22 = 1e10f, md23 = 1e10f;
    float md24 = 1e10f, md25 = 1e10f, md26 = 1e10f, md27 = 1e10f;
    float md28 = 1e10f, md29 = 1e10f, md30 = 1e10f, md31 = 1e10f;

    // wave bbox over its 2048-point Morton segment (one-time)
    float lx = 1e30f, ly = 1e30f, lz = 1e30f, hx = -1e30f, hy = -1e30f, hz = -1e30f;
#pragma unroll
    for (int j = 0; j < 32; ++j) {
        float4 v = spl[j * 64];
        lx = fminf(lx, v.x); hx = fmaxf(hx, v.x);
        ly = fminf(ly, v.y); hy = fmaxf(hy, v.y);
        lz = fminf(lz, v.z); hz = fmaxf(hz, v.z);
    }
#pragma unroll
    for (int off = 1; off <= 32; off <<= 1) {
        lx = fminf(lx, __shfl_xor(lx, off));
        ly = fminf(ly, __shfl_xor(ly, off));
        lz = fminf(lz, __shfl_xor(lz, off));
        hx = fmaxf(hx, __shfl_xor(hx, off));
        hy = fmaxf(hy, __shfl_xor(hy, off));
        hz = fmaxf(hz, __shfl_xor(hz, off));
    }

    __shared__ unsigned long long skey[2][FWAVE];
    __shared__ float4 scd[2][FWAVE];
    __shared__ float cent_lds[MCENT * 3];

    float cx = xb[0], cy = xb[1], cz = xb[2];

    float bv = -1.0f; int bpid = 0x7fffffff;
    float bx = 0.f, by = 0.f, bz = 0.f;
    unsigned long long mykey = 0, wkey = 0;

    for (int m = 0; m < MCENT; ++m) {
        if (tid == 0) {
            cent_lds[m * 3 + 0] = cx;
            cent_lds[m * 3 + 1] = cy;
            cent_lds[m * 3 + 2] = cz;
        }
        if (m == MCENT - 1) break;

        // wave-uniform exact prune: no md in this wave's segment can change
        float tx = fmaxf(fmaxf(lx - cx, cx - hx), 0.0f);
        float ty = fmaxf(fmaxf(ly - cy, cy - hy), 0.0f);
        float tz = fmaxf(fmaxf(lz - cz, cz - hz), 0.0f);
        float lb = tx * tx + ty * ty;
        lb = lb + tz * tz;
        bool active = (m == 0) || (lb * 0.999f < bv);

        if (__any(active)) {  // wave-uniform
            bv = -1.0f; bpid = 0x7fffffff;
            BATCH8(0, md0,  md1,  md2,  md3,  md4,  md5,  md6,  md7)
            BATCH8(1, md8,  md9,  md10, md11, md12, md13, md14, md15)
            BATCH8(2, md16, md17, md18, md19, md20, md21, md22, md23)
            BATCH8(3, md24, md25, md26, md27, md28, md29, md30, md31)
            mykey = ((unsigned long long)__float_as_uint(bv) << 32)
                  | (unsigned)(((16383 - bpid) << 3) | wid);
            unsigned long long k = mykey;
#pragma unroll
            for (int off = 1; off <= 32; off <<= 1) {
                unsigned long long o = shflxor_u64(k, off);
                if (o > k) k = o;
            }
            wkey = k;
        }
        const int pb = m & 1;
        if (mykey == wkey) {  // unique owner (pid embedded); runs every iter
            skey[pb][wid] = wkey;
            scd[pb][wid] = make_float4(bx, by, bz, 0.0f);
        }
        __syncthreads();

        // redundant per-wave reduce of 8 slots (4 pairs + depth-2 tree)
        unsigned long long t0, t1, t2, t3;
        {
            unsigned long long a, c;
            a = skey[pb][0]; c = skey[pb][1]; t0 = a > c ? a : c;
            a = skey[pb][2]; c = skey[pb][3]; t1 = a > c ? a : c;
            a = skey[pb][4]; c = skey[pb][5]; t2 = a > c ? a : c;
            a = skey[pb][6]; c = skey[pb][7]; t3 = a > c ? a : c;
        }
        if (t2 > t0) t0 = t2;
        if (t3 > t1) t1 = t3;
        if (t1 > t0) t0 = t1;
        float4 w = scd[pb][(unsigned)t0 & 7u];
        cx = w.x; cy = w.y; cz = w.z;
    }

    __syncthreads();
    for (int i = tid; i < MCENT * 3; i += FTHR) cb[i] = cent_lds[i];
}

// ---------------- Ball query + group ----------------
__global__ __launch_bounds__(256) void ballq_kernel(const float* __restrict__ xyz,
                                                    const float* __restrict__ cent,
                                                    float* __restrict__ grouped) {
#pragma clang fp contract(off)
    const int lane = threadIdx.x & 63;
    const int wib = threadIdx.x >> 6;
    const int cid = blockIdx.x * 4 + wib;
    const int b = cid >> 10;
    const float* xb = xyz + (size_t)b * NPTS * 3;
    const float* c = cent + (size_t)cid * 3;
    float cx = c[0], cy = c[1], cz = c[2];
    float* g = grouped + (size_t)cid * NSAMPLE * 3;

    const float R2 = (float)(0.1 * 0.1);

    int total = 0;
    int first_p = -1;

    for (int p0 = 0; p0 < NPTS && total < NSAMPLE; p0 += 64) {
        int p = p0 + lane;
        float x = xb[p * 3 + 0];
        float y = xb[p * 3 + 1];
        float z = xb[p * 3 + 2];
        float dx = x - cx;
        float dy = y - cy;
        float dz = z - cz;
        float d = dx * dx + dy * dy;
        d = d + dz * dz;
        bool hit = d < R2;
        unsigned long long mask = __ballot(hit);
        if (hit) {
            unsigned int mb = __builtin_amdgcn_mbcnt_lo((unsigned int)mask, 0u);
            mb = __builtin_amdgcn_mbcnt_hi((unsigned int)(mask >> 32), mb);
            int pos = total + (int)mb;
            if (pos < NSAMPLE) {
                g[pos * 3 + 0] = dx;
                g[pos * 3 + 1] = dy;
                g[pos * 3 + 2] = dz;
            }
        }
        if (first_p < 0 && mask != 0ull) first_p = p0 + __builtin_ctzll(mask);
        total += __popcll(mask);
    }

    int sel = total < NSAMPLE ? total : NSAMPLE;
    if (sel < NSAMPLE) {
        float fx = xb[first_p * 3 + 0] - cx;
        float fy = xb[first_p * 3 + 1] - cy;
        float fz = xb[first_p * 3 + 2] - cz;
        int s = lane;
        if (s >= sel && s < NSAMPLE) {
            g[s * 3 + 0] = fx;
            g[s * 3 + 1] = fy;
            g[s * 3 + 2] = fz;
        }
    }
}

extern "C" void kernel_launch(void* const* d_in, const int* in_sizes, int n_in,
                              void* d_out, int out_size, void* d_ws, size_t ws_size,
                              hipStream_t stream) {
    const float* xyz = (const float*)d_in[0];
    float* out = (float*)d_out;
    float* grouped = out;
    float* cent = out + (size_t)BATCH * MCENT * NSAMPLE * 3;
    float4* sorted = (float4*)d_ws;  // 4 MiB

    sort_kernel<<<BATCH, 1024, 0, stream>>>(xyz, sorted);
    fps_kernel<<<BATCH, FTHR, 0, stream>>>(xyz, sorted, cent);
    ballq_kernel<<<(BATCH * MCENT) / 4, 256, 0, stream>>>(xyz, cent, grouped);
}